// Round 7
// baseline (5379.320 us; speedup 1.0000x reference)
//
#include <hip/hip_runtime.h>
#include <math.h>

#define NPTS 2048
#define NB 8
#define KNN 20
#define EPSI 1e-5f
#define SLOPE 0.2f

typedef short bf16x8 __attribute__((ext_vector_type(8)));
typedef float f32x4 __attribute__((ext_vector_type(4)));

__device__ __forceinline__ unsigned short f2bf(float x) {
    union { float f; unsigned u; } v; v.f = x;
    unsigned r = v.u + 0x7FFF + ((v.u >> 16) & 1u);
    return (unsigned short)(r >> 16);
}
__device__ __forceinline__ float bf2f(unsigned short h) {
    union { unsigned u; float f; } v; v.u = ((unsigned)h) << 16; return v.f;
}

__device__ __forceinline__ void gl_lds16(const unsigned short* g, unsigned short* l) {
    __builtin_amdgcn_global_load_lds(
        (const __attribute__((address_space(1))) void*)g,
        (__attribute__((address_space(3))) void*)l, 16, 0, 0);
}

// ---------------- transpose (B,N,3) -> (B,3,N) ----------------
__global__ __launch_bounds__(256) void transpose_kernel(const float* __restrict__ xin,
                                                        float* __restrict__ xc) {
    int g = blockIdx.x * 256 + threadIdx.x;
    int b = g / NPTS, n = g % NPTS;
    float v0 = xin[(size_t)g * 3 + 0];
    float v1 = xin[(size_t)g * 3 + 1];
    float v2 = xin[(size_t)g * 3 + 2];
    xc[((size_t)b * 3 + 0) * NPTS + n] = v0;
    xc[((size_t)b * 3 + 1) * NPTS + n] = v1;
    xc[((size_t)b * 3 + 2) * NPTS + n] = v2;
}

// ---------------- xx[b,n] = sum_c x[b,c,n]^2 ----------------
__global__ __launch_bounds__(256) void xx_kernel(const float* __restrict__ x, int bstride, int C,
                                                 float* __restrict__ xx) {
    int g = blockIdx.x * 256 + threadIdx.x;
    int b = g / NPTS, n = g % NPTS;
    const float* p = x + (size_t)b * bstride + n;
    float s = 0.f;
    for (int c = 0; c < C; ++c) { float v = p[(size_t)c * NPTS]; s += v * v; }
    xx[g] = s;
}

// ---------------- fused pd-GEMM + exact top-20 ----------------
// Block: 64 rows x all 2048 cols (16 col-tiles of 128). fp32 GEMM with the same
// ascending-c FMA order as the previous pd_gemm2 (bitwise-identical pd values).
// Wave 0's 64 threads own one row each, maintaining a 20-min-heap of u64 keys
// (orderable(value)<<32 | ~col) == jax (value desc, index asc) top-20 set.
__global__ __launch_bounds__(256) void knn_fused(const float* __restrict__ x, int bstride, int C,
                                                 const float* __restrict__ xx,
                                                 int* __restrict__ idxout) {
    __shared__ float As[2][16][64];
    __shared__ float Bs[2][16][128];
    __shared__ float pdt[64][129];                 // +1 pad: scan reads conflict-free
    __shared__ unsigned long long heap[64][21];    // stride 21 to spread banks
    int b = blockIdx.y;
    int R0 = blockIdx.x * 64;
    int tid = threadIdx.x;
    int tr = tid >> 4, tc = tid & 15;              // GEMM: rows tr*4.., cols tc*4 & 64+tc*4
    const float* xb = x + (size_t)b * bstride;
    const float* xxb = xx + (size_t)b * NPTS;

    int cnt = 0;
    unsigned long long minkey = 0ull;
    unsigned long long* hp = heap[tid & 63];

    for (int ct = 0; ct < 16; ++ct) {
        int M0 = ct * 128;
        float acc[4][8] = {};

        // stage chunk c0=0 into buffer 0
        {
            int KC = min(16, C);
            {
                int t = tid;                        // As: 256 float4 slots
                int cc = t >> 4, j4 = (t & 15) * 4;
                float4 v = make_float4(0.f, 0.f, 0.f, 0.f);
                if (cc < KC) v = *(const float4*)&xb[(size_t)cc * NPTS + R0 + j4];
                *(float4*)&As[0][cc][j4] = v;
            }
            for (int t = tid; t < 512; t += 256) {  // Bs: 512 float4 slots
                int cc = t >> 5, j4 = (t & 31) * 4;
                float4 v = make_float4(0.f, 0.f, 0.f, 0.f);
                if (cc < KC) v = *(const float4*)&xb[(size_t)cc * NPTS + M0 + j4];
                *(float4*)&Bs[0][cc][j4] = v;
            }
        }
        __syncthreads();

        int cur = 0;
        for (int c0 = 0; c0 < C; c0 += 16) {
            int c1 = c0 + 16;
            if (c1 < C) {
                int KC = min(16, C - c1);
                {
                    int t = tid;
                    int cc = t >> 4, j4 = (t & 15) * 4;
                    float4 v = make_float4(0.f, 0.f, 0.f, 0.f);
                    if (cc < KC) v = *(const float4*)&xb[(size_t)(c1 + cc) * NPTS + R0 + j4];
                    *(float4*)&As[cur ^ 1][cc][j4] = v;
                }
                for (int t = tid; t < 512; t += 256) {
                    int cc = t >> 5, j4 = (t & 31) * 4;
                    float4 v = make_float4(0.f, 0.f, 0.f, 0.f);
                    if (cc < KC) v = *(const float4*)&xb[(size_t)(c1 + cc) * NPTS + M0 + j4];
                    *(float4*)&Bs[cur ^ 1][cc][j4] = v;
                }
            }
            int KC = min(16, C - c0);
            if (KC == 16) {
                #pragma unroll
                for (int cc = 0; cc < 16; ++cc) {
                    float av[4], bv[8];
                    *(float4*)&av[0] = *(const float4*)&As[cur][cc][tr * 4];
                    *(float4*)&bv[0] = *(const float4*)&Bs[cur][cc][tc * 4];
                    *(float4*)&bv[4] = *(const float4*)&Bs[cur][cc][64 + tc * 4];
                    #pragma unroll
                    for (int i = 0; i < 4; ++i)
                        #pragma unroll
                        for (int j = 0; j < 8; ++j)
                            acc[i][j] += av[i] * bv[j];
                }
            } else {
                for (int cc = 0; cc < KC; ++cc) {
                    float av[4], bv[8];
                    *(float4*)&av[0] = *(const float4*)&As[cur][cc][tr * 4];
                    *(float4*)&bv[0] = *(const float4*)&Bs[cur][cc][tc * 4];
                    *(float4*)&bv[4] = *(const float4*)&Bs[cur][cc][64 + tc * 4];
                    #pragma unroll
                    for (int i = 0; i < 4; ++i)
                        #pragma unroll
                        for (int j = 0; j < 8; ++j)
                            acc[i][j] += av[i] * bv[j];
                }
            }
            __syncthreads();
            cur ^= 1;
        }

        // write pd tile (2*acc - xx_n - xx_m) into LDS
        #pragma unroll
        for (int i = 0; i < 4; ++i) {
            int r = tr * 4 + i;
            float xnr = xxb[R0 + r];
            #pragma unroll
            for (int j = 0; j < 4; ++j) {
                pdt[r][tc * 4 + j]      = 2.f * acc[i][j]     - xnr - xxb[M0 + tc * 4 + j];
                pdt[r][64 + tc * 4 + j] = 2.f * acc[i][j + 4] - xnr - xxb[M0 + 64 + tc * 4 + j];
            }
        }
        __syncthreads();

        // scan: wave 0, one row per lane
        if (tid < 64) {
            for (int j = 0; j < 128; ++j) {
                float v = pdt[tid][j];
                unsigned s = __float_as_uint(v);
                unsigned ov = (s & 0x80000000u) ? ~s : (s | 0x80000000u);
                unsigned gcol = (unsigned)(M0 + j);
                unsigned long long key = ((unsigned long long)ov << 32) | (unsigned)(~gcol);
                if (cnt < 20) {
                    int i = cnt++;
                    hp[i] = key;
                    while (i > 0) {
                        int p = (i - 1) >> 1;
                        if (hp[p] > hp[i]) {
                            unsigned long long t2 = hp[p]; hp[p] = hp[i]; hp[i] = t2; i = p;
                        } else break;
                    }
                    if (cnt == 20) minkey = hp[0];
                } else if (key > minkey) {
                    int i = 0;
                    for (;;) {
                        int l = 2 * i + 1;
                        if (l >= 20) break;
                        int m = (l + 1 < 20 && hp[l + 1] < hp[l]) ? l + 1 : l;
                        if (hp[m] < key) { hp[i] = hp[m]; i = m; } else break;
                    }
                    hp[i] = key;
                    minkey = hp[0];
                }
            }
        }
        __syncthreads();
    }

    if (tid < 64) {
        int row = R0 + tid;
        #pragma unroll
        for (int t = 0; t < 20; ++t)
            idxout[((size_t)b * NPTS + row) * KNN + t] = (int)~(unsigned)hp[t];
    }
}

// ---------------- y = w_d * x ; z = (w_c - w_d) * x  (64n x 64o tile, 4x4/thread) ----------------
__global__ __launch_bounds__(256) void yz_gemm2(const float* __restrict__ x, int bstride, int C, int O,
                                                const float* __restrict__ w,
                                                float* __restrict__ y, float* __restrict__ z) {
    __shared__ float Xs[32][64];
    __shared__ float Wd[32][68];   // +4 pad: staging writes 32-way -> 4-way
    __shared__ float Wz[32][68];
    int b = blockIdx.z;
    int mbase = blockIdx.x * 64;
    int obase = blockIdx.y * 64;
    int tid = threadIdx.x;
    int nq = tid & 15, oq = tid >> 4;
    const float* xb = x + (size_t)b * bstride;
    int C2 = 2 * C;
    float accy[4][4] = {}, accz[4][4] = {};

    for (int c0 = 0; c0 < C; c0 += 32) {
        int KC = min(32, C - c0);
        for (int t = tid; t < 512; t += 256) {
            int cc = t >> 4, j4 = (t & 15) * 4;
            float4 v = make_float4(0.f, 0.f, 0.f, 0.f);
            if (cc < KC) v = *(const float4*)&xb[(size_t)(c0 + cc) * NPTS + mbase + j4];
            *(float4*)&Xs[cc][j4] = v;
        }
        for (int t = tid; t < 2048; t += 256) {
            int o = t >> 5, cc = t & 31;
            float wd = 0.f, wz = 0.f;
            if (cc < KC) {
                wd = w[(size_t)(obase + o) * C2 + c0 + cc];
                wz = w[(size_t)(obase + o) * C2 + C + c0 + cc] - wd;
            }
            Wd[cc][o] = wd; Wz[cc][o] = wz;
        }
        __syncthreads();
        for (int cc = 0; cc < KC; ++cc) {
            float xv[4], wdv[4], wzv[4];
            *(float4*)xv  = *(float4*)&Xs[cc][nq * 4];
            *(float4*)wdv = *(float4*)&Wd[cc][oq * 4];
            *(float4*)wzv = *(float4*)&Wz[cc][oq * 4];
            #pragma unroll
            for (int i = 0; i < 4; ++i)
                #pragma unroll
                for (int j = 0; j < 4; ++j) {
                    accy[i][j] += wdv[i] * xv[j];
                    accz[i][j] += wzv[i] * xv[j];
                }
        }
        __syncthreads();
    }

    #pragma unroll
    for (int i = 0; i < 4; ++i) {
        size_t off = ((size_t)b * O + obase + oq * 4 + i) * NPTS + mbase + nq * 4;
        *(float4*)&y[off] = make_float4(accy[i][0], accy[i][1], accy[i][2], accy[i][3]);
        *(float4*)&z[off] = make_float4(accz[i][0], accz[i][1], accz[i][2], accz[i][3]);
    }
}

// ---------------- gather + instnorm stats + leaky, 4 channels per block ----------------
__global__ __launch_bounds__(256) void gather_norm2(const float* __restrict__ y,
                                                    const float* __restrict__ z,
                                                    const int* __restrict__ idx,
                                                    float* __restrict__ cat, int coff, int O) {
    __shared__ float yt[NPTS][4];
    __shared__ float red[32];
    int og = blockIdx.x * 4, b = blockIdx.y;
    int tid = threadIdx.x;

    for (int n = tid; n < NPTS; n += 256) {
        float4 v;
        v.x = y[((size_t)b * O + og + 0) * NPTS + n];
        v.y = y[((size_t)b * O + og + 1) * NPTS + n];
        v.z = y[((size_t)b * O + og + 2) * NPTS + n];
        v.w = y[((size_t)b * O + og + 3) * NPTS + n];
        *(float4*)&yt[n][0] = v;
    }
    __syncthreads();

    float s1[4] = {0.f, 0.f, 0.f, 0.f}, s2[4] = {0.f, 0.f, 0.f, 0.f};
    float hm[4][8];
    for (int r = 0; r < 8; ++r) {
        int n = r * 256 + tid;
        const int* ip = idx + ((size_t)b * NPTS + n) * KNN;
        float zv[4], mx[4];
        #pragma unroll
        for (int j = 0; j < 4; ++j) {
            zv[j] = z[((size_t)b * O + og + j) * NPTS + n];
            mx[j] = -INFINITY;
        }
        #pragma unroll
        for (int k = 0; k < KNN; ++k) {
            int id = ip[k];
            float4 yv = *(float4*)&yt[id][0];
            float h0 = yv.x + zv[0]; s1[0] += h0; s2[0] += h0 * h0; mx[0] = fmaxf(mx[0], h0);
            float h1 = yv.y + zv[1]; s1[1] += h1; s2[1] += h1 * h1; mx[1] = fmaxf(mx[1], h1);
            float h2 = yv.z + zv[2]; s1[2] += h2; s2[2] += h2 * h2; mx[2] = fmaxf(mx[2], h2);
            float h3 = yv.w + zv[3]; s1[3] += h3; s2[3] += h3 * h3; mx[3] = fmaxf(mx[3], h3);
        }
        #pragma unroll
        for (int j = 0; j < 4; ++j) hm[j][r] = mx[j];
    }
    #pragma unroll
    for (int off = 32; off > 0; off >>= 1)
        #pragma unroll
        for (int j = 0; j < 4; ++j) {
            s1[j] += __shfl_xor(s1[j], off);
            s2[j] += __shfl_xor(s2[j], off);
        }
    int wv = tid >> 6, lane = tid & 63;
    if (lane == 0)
        #pragma unroll
        for (int j = 0; j < 4; ++j) { red[j * 8 + wv] = s1[j]; red[j * 8 + 4 + wv] = s2[j]; }
    __syncthreads();
    const float inv = 1.f / (float)(NPTS * KNN);
    #pragma unroll
    for (int j = 0; j < 4; ++j) {
        float S1 = red[j * 8 + 0] + red[j * 8 + 1] + red[j * 8 + 2] + red[j * 8 + 3];
        float S2 = red[j * 8 + 4] + red[j * 8 + 5] + red[j * 8 + 6] + red[j * 8 + 7];
        float mean = S1 * inv;
        float var = S2 * inv - mean * mean;
        float rs = 1.f / sqrtf(var + EPSI);
        float* dst = cat + ((size_t)b * 512 + coff + og + j) * NPTS;
        #pragma unroll
        for (int r = 0; r < 8; ++r) {
            float vv = (hm[j][r] - mean) * rs;
            dst[r * 256 + tid] = vv >= 0.f ? vv : SLOPE * vv;
        }
    }
}

// ---------------- w5 -> K-concat hi/lo bf16: wcat[o][0:512]=hi, [512:1024]=lo ----------------
__global__ __launch_bounds__(256) void w5_prep(const float* __restrict__ w5,
                                               unsigned short* __restrict__ wcat) {
    int i = blockIdx.x * 256 + threadIdx.x;
    int o = i >> 9, c = i & 511;
    float x = w5[i];
    unsigned short h = f2bf(x);
    wcat[(size_t)o * 1024 + c] = h;
    wcat[(size_t)o * 1024 + 512 + c] = f2bf(x - bf2f(h));
}

// ---------------- cat (B,512,N) -> point-major K-concat bf16 ----------------
__global__ __launch_bounds__(256) void catT_prep(const float* __restrict__ cat,
                                                 unsigned short* __restrict__ ct) {
    __shared__ float t[32][33];
    int b = blockIdx.z;
    int n0 = blockIdx.x * 32, c0 = blockIdx.y * 32;
    int tx = threadIdx.x & 31, ty = threadIdx.x >> 5;
    #pragma unroll
    for (int r = 0; r < 4; ++r) {
        int ci = ty + r * 8;
        t[ci][tx] = cat[((size_t)b * 512 + c0 + ci) * NPTS + n0 + tx];
    }
    __syncthreads();
    #pragma unroll
    for (int r = 0; r < 4; ++r) {
        int ni = ty + r * 8;
        float x = t[tx][ni];
        unsigned short h = f2bf(x);
        size_t off = ((size_t)b * NPTS + n0 + ni) * 1024 + c0 + tx;
        ct[off] = h;
        ct[off + 512] = f2bf(x - bf2f(h));
    }
}

// ---------------- final GEMM: h[b] = w5 (512x1024 bf16) x ct[b] (2048x1024 bf16)^T ----------------
__global__ __launch_bounds__(256, 2) void final_gemm_mfma2(const unsigned short* __restrict__ wcat,
                                                           const unsigned short* __restrict__ ct,
                                                           float* __restrict__ h) {
    __shared__ unsigned short smem[4 * 8192];   // [buf][A|B][128][64]
    int b = blockIdx.z;
    int nbase = blockIdx.x * 128, obase = blockIdx.y * 128;
    int tid = threadIdx.x;
    int w = tid >> 6, l = tid & 63;
    int wr = (w >> 1) * 64, wc = (w & 1) * 64;
    int lr = l & 15, lq = l >> 4;

    const unsigned short* Ag = wcat + (size_t)obase * 1024;
    const unsigned short* Bg = ct + ((size_t)b * NPTS + nbase) * 1024;

    int rw = l >> 3, g = l & 7, sg = g ^ rw;   // stage swizzle (involution)

    f32x4 acc[4][4] = {};

    auto STAGE = [&](int buf, int k0) {
        unsigned short* Ad = smem + buf * 16384;
        unsigned short* Bd = Ad + 8192;
        #pragma unroll
        for (int pass = 0; pass < 4; ++pass) {
            int rbase = pass * 32 + w * 8;
            int row = rbase + rw;
            gl_lds16(Ag + (size_t)row * 1024 + k0 + sg * 8, Ad + rbase * 64);
            gl_lds16(Bg + (size_t)row * 1024 + k0 + sg * 8, Bd + rbase * 64);
        }
    };

    STAGE(0, 0);
    __syncthreads();

    int cur = 0;
    for (int kt = 0; kt < 16; ++kt) {
        if (kt < 15) STAGE(cur ^ 1, (kt + 1) * 64);
        const unsigned short* As = smem + cur * 16384;
        const unsigned short* Bs = As + 8192;
        #pragma unroll
        for (int kk = 0; kk < 2; ++kk) {
            bf16x8 af[4], bf[4];
            int gl = kk * 4 + lq;
            #pragma unroll
            for (int mi = 0; mi < 4; ++mi) {
                int row = wr + mi * 16 + lr;
                af[mi] = *(const bf16x8*)&As[row * 64 + ((gl ^ (row & 7)) * 8)];
            }
            #pragma unroll
            for (int ni = 0; ni < 4; ++ni) {
                int row = wc + ni * 16 + lr;
                bf[ni] = *(const bf16x8*)&Bs[row * 64 + ((gl ^ (row & 7)) * 8)];
            }
            #pragma unroll
            for (int mi = 0; mi < 4; ++mi)
                #pragma unroll
                for (int ni = 0; ni < 4; ++ni)
                    acc[mi][ni] = __builtin_amdgcn_mfma_f32_16x16x32_bf16(af[mi], bf[ni], acc[mi][ni], 0, 0, 0);
        }
        __syncthreads();
        cur ^= 1;
    }

    int orow0 = obase + wr + lq * 4;
    int ncol0 = nbase + wc + lr;
    #pragma unroll
    for (int mi = 0; mi < 4; ++mi)
        #pragma unroll
        for (int r = 0; r < 4; ++r)
            #pragma unroll
            for (int ni = 0; ni < 4; ++ni)
                h[((size_t)b * 512 + orow0 + mi * 16 + r) * NPTS + ncol0 + ni * 16] = acc[mi][ni][r];
}

// ---------------- final instnorm over n + leaky ----------------
__global__ __launch_bounds__(256) void final_norm(const float* __restrict__ h,
                                                  float* __restrict__ out) {
    __shared__ float red[8];
    int o = blockIdx.x, b = blockIdx.y;
    int tid = threadIdx.x;
    const float* hr = h + ((size_t)b * 512 + o) * NPTS;
    float s1 = 0.f, s2 = 0.f;
    float v[8];
    #pragma unroll
    for (int r = 0; r < 8; ++r) {
        v[r] = hr[r * 256 + tid];
        s1 += v[r]; s2 += v[r] * v[r];
    }
    #pragma unroll
    for (int off = 32; off > 0; off >>= 1) {
        s1 += __shfl_xor(s1, off);
        s2 += __shfl_xor(s2, off);
    }
    int wv = tid >> 6, lane = tid & 63;
    if (lane == 0) { red[wv] = s1; red[4 + wv] = s2; }
    __syncthreads();
    float S1 = red[0] + red[1] + red[2] + red[3];
    float S2 = red[4] + red[5] + red[6] + red[7];
    const float inv = 1.f / (float)NPTS;
    float mean = S1 * inv;
    float var = S2 * inv - mean * mean;
    float rs = 1.f / sqrtf(var + EPSI);
    float* dst = out + ((size_t)b * 512 + o) * NPTS;
    #pragma unroll
    for (int r = 0; r < 8; ++r) {
        float vv = (v[r] - mean) * rs;
        dst[r * 256 + tid] = vv >= 0.f ? vv : SLOPE * vv;
    }
}

extern "C" void kernel_launch(void* const* d_in, const int* in_sizes, int n_in,
                              void* d_out, int out_size, void* d_ws, size_t ws_size,
                              hipStream_t stream) {
    const float* x_in = (const float*)d_in[0];
    const float* w1 = (const float*)d_in[1];
    const float* w2 = (const float*)d_in[2];
    const float* w3 = (const float*)d_in[3];
    const float* w4 = (const float*)d_in[4];
    const float* w5 = (const float*)d_in[5];
    float* out = (float*)d_out;
    float* ws = (float*)d_ws;

    // workspace (floats):
    // region [0, 8388608): y+z during layers; ct (bf16, 33.5MB) at final
    // idx 327680 ints; xx 16384; xc 49152; cat 8388608 (reused as h); wcat 1MB bf16
    float* region = ws;
    float* yb = region;
    float* zb = region + 4194304;
    int* idxb = (int*)(ws + 8388608);
    float* xxb = ws + 8388608 + 327680;
    float* xcb = xxb + NB * NPTS;
    float* cat = xcb + NB * 3 * NPTS;
    unsigned short* wcat = (unsigned short*)(cat + 8388608);
    unsigned short* ct = (unsigned short*)region;
    float* hb = cat;   // cat is dead after catT_prep

    transpose_kernel<<<NB * NPTS / 256, 256, 0, stream>>>(x_in, xcb);
    w5_prep<<<512 * 512 / 256, 256, 0, stream>>>(w5, wcat);

    const float* srcs[4] = {xcb, cat, cat + (size_t)64 * NPTS, cat + (size_t)128 * NPTS};
    int bstr[4] = {3 * NPTS, 512 * NPTS, 512 * NPTS, 512 * NPTS};
    int Cin[4] = {3, 64, 64, 128};
    int Oc[4] = {64, 64, 128, 256};
    const float* wl[4] = {w1, w2, w3, w4};
    int coffs[4] = {0, 64, 128, 256};

    for (int li = 0; li < 4; ++li) {
        xx_kernel<<<NB * NPTS / 256, 256, 0, stream>>>(srcs[li], bstr[li], Cin[li], xxb);
        knn_fused<<<dim3(NPTS / 64, NB), 256, 0, stream>>>(srcs[li], bstr[li], Cin[li], xxb, idxb);
        yz_gemm2<<<dim3(NPTS / 64, Oc[li] / 64, NB), 256, 0, stream>>>(
            srcs[li], bstr[li], Cin[li], Oc[li], wl[li], yb, zb);
        gather_norm2<<<dim3(Oc[li] / 4, NB), 256, 0, stream>>>(yb, zb, idxb, cat, coffs[li], Oc[li]);
    }

    catT_prep<<<dim3(NPTS / 32, 512 / 32, NB), 256, 0, stream>>>(cat, ct);
    final_gemm_mfma2<<<dim3(NPTS / 128, 512 / 128, NB), 256, 0, stream>>>(wcat, ct, hb);
    final_norm<<<dim3(512, NB), 256, 0, stream>>>(hb, out);
}

// Round 8
// 1327.285 us; speedup vs baseline: 4.0529x; 4.0529x over previous
//
#include <hip/hip_runtime.h>
#include <math.h>

#define NPTS 2048
#define NB 8
#define KNN 20
#define EPSI 1e-5f
#define SLOPE 0.2f
#define CHUNK 512

typedef short bf16x8 __attribute__((ext_vector_type(8)));
typedef float f32x4 __attribute__((ext_vector_type(4)));

__device__ __forceinline__ unsigned short f2bf(float x) {
    union { float f; unsigned u; } v; v.f = x;
    unsigned r = v.u + 0x7FFF + ((v.u >> 16) & 1u);
    return (unsigned short)(r >> 16);
}
__device__ __forceinline__ float bf2f(unsigned short h) {
    union { unsigned u; float f; } v; v.u = ((unsigned)h) << 16; return v.f;
}

__device__ __forceinline__ void gl_lds16(const unsigned short* g, unsigned short* l) {
    __builtin_amdgcn_global_load_lds(
        (const __attribute__((address_space(1))) void*)g,
        (__attribute__((address_space(3))) void*)l, 16, 0, 0);
}

// ---------------- transpose (B,N,3) -> (B,3,N) ----------------
__global__ __launch_bounds__(256) void transpose_kernel(const float* __restrict__ xin,
                                                        float* __restrict__ xc) {
    int g = blockIdx.x * 256 + threadIdx.x;
    int b = g / NPTS, n = g % NPTS;
    float v0 = xin[(size_t)g * 3 + 0];
    float v1 = xin[(size_t)g * 3 + 1];
    float v2 = xin[(size_t)g * 3 + 2];
    xc[((size_t)b * 3 + 0) * NPTS + n] = v0;
    xc[((size_t)b * 3 + 1) * NPTS + n] = v1;
    xc[((size_t)b * 3 + 2) * NPTS + n] = v2;
}

// ---------------- xx[b,n] = sum_c x[b,c,n]^2 ----------------
__global__ __launch_bounds__(256) void xx_kernel(const float* __restrict__ x, int bstride, int C,
                                                 float* __restrict__ xx) {
    int g = blockIdx.x * 256 + threadIdx.x;
    int b = g / NPTS, n = g % NPTS;
    const float* p = x + (size_t)b * bstride + n;
    float s = 0.f;
    for (int c = 0; c < C; ++c) { float v = p[(size_t)c * NPTS]; s += v * v; }
    xx[g] = s;
}

// ---------------- pd chunk GEMM: 128x128 tile, 8x8 acc, fp32, double-buffered ----------------
// Column mapping per thread: {tx*4..+3, 64+tx*4..+3} -> B-fragment LDS reads are
// two float4 loads with only 2-way bank aliasing (the old tx*8 b128 read was 4-way).
// Per-element FMA order (ascending c) identical to the round-4 passing kernel:
// pd values are bitwise unchanged.
__global__ __launch_bounds__(256) void pd_gemm3(const float* __restrict__ x, int bstride, int C,
                                                const float* __restrict__ xx,
                                                float* __restrict__ pd, int r0) {
    __shared__ float As[2][16][128];
    __shared__ float Bs[2][16][128];
    int b = blockIdx.z;
    int nbase_l = blockIdx.y * 128;
    int mbase = blockIdx.x * 128;
    int tx = threadIdx.x & 15, ty = threadIdx.x >> 4;
    int tid = threadIdx.x;
    float acc[8][8] = {};
    const float* xb = x + (size_t)b * bstride;

    {
        int KC = min(16, C);
        for (int t = tid; t < 512; t += 256) {
            int cc = t >> 5, j4 = (t & 31) * 4;
            float4 av = make_float4(0.f, 0.f, 0.f, 0.f), bv = av;
            if (cc < KC) {
                av = *(const float4*)&xb[(size_t)cc * NPTS + r0 + nbase_l + j4];
                bv = *(const float4*)&xb[(size_t)cc * NPTS + mbase + j4];
            }
            *(float4*)&As[0][cc][j4] = av;
            *(float4*)&Bs[0][cc][j4] = bv;
        }
    }
    __syncthreads();

    int cur = 0;
    for (int c0 = 0; c0 < C; c0 += 16) {
        int c1 = c0 + 16;
        if (c1 < C) {
            int KC = min(16, C - c1);
            for (int t = tid; t < 512; t += 256) {
                int cc = t >> 5, j4 = (t & 31) * 4;
                float4 av = make_float4(0.f, 0.f, 0.f, 0.f), bv = av;
                if (cc < KC) {
                    av = *(const float4*)&xb[(size_t)(c1 + cc) * NPTS + r0 + nbase_l + j4];
                    bv = *(const float4*)&xb[(size_t)(c1 + cc) * NPTS + mbase + j4];
                }
                *(float4*)&As[cur ^ 1][cc][j4] = av;
                *(float4*)&Bs[cur ^ 1][cc][j4] = bv;
            }
        }
        int KC = min(16, C - c0);
        if (KC == 16) {
            #pragma unroll
            for (int cc = 0; cc < 16; ++cc) {
                float av[8], bv[8];
                *(float4*)&av[0] = *(const float4*)&As[cur][cc][ty * 8];
                *(float4*)&av[4] = *(const float4*)&As[cur][cc][ty * 8 + 4];
                *(float4*)&bv[0] = *(const float4*)&Bs[cur][cc][tx * 4];
                *(float4*)&bv[4] = *(const float4*)&Bs[cur][cc][64 + tx * 4];
                #pragma unroll
                for (int i = 0; i < 8; ++i)
                    #pragma unroll
                    for (int j = 0; j < 8; ++j)
                        acc[i][j] += av[i] * bv[j];
            }
        } else {
            for (int cc = 0; cc < KC; ++cc) {
                float av[8], bv[8];
                *(float4*)&av[0] = *(const float4*)&As[cur][cc][ty * 8];
                *(float4*)&av[4] = *(const float4*)&As[cur][cc][ty * 8 + 4];
                *(float4*)&bv[0] = *(const float4*)&Bs[cur][cc][tx * 4];
                *(float4*)&bv[4] = *(const float4*)&Bs[cur][cc][64 + tx * 4];
                #pragma unroll
                for (int i = 0; i < 8; ++i)
                    #pragma unroll
                    for (int j = 0; j < 8; ++j)
                        acc[i][j] += av[i] * bv[j];
            }
        }
        __syncthreads();
        cur ^= 1;
    }

    const float* xxb = xx + (size_t)b * NPTS;
    #pragma unroll
    for (int i = 0; i < 8; ++i) {
        int nl = nbase_l + ty * 8 + i;
        float xn = xxb[r0 + nl];
        float4 o0, o1;
        o0.x = 2.f * acc[i][0] - xn - xxb[mbase + tx*4 + 0];
        o0.y = 2.f * acc[i][1] - xn - xxb[mbase + tx*4 + 1];
        o0.z = 2.f * acc[i][2] - xn - xxb[mbase + tx*4 + 2];
        o0.w = 2.f * acc[i][3] - xn - xxb[mbase + tx*4 + 3];
        o1.x = 2.f * acc[i][4] - xn - xxb[mbase + 64 + tx*4 + 0];
        o1.y = 2.f * acc[i][5] - xn - xxb[mbase + 64 + tx*4 + 1];
        o1.z = 2.f * acc[i][6] - xn - xxb[mbase + 64 + tx*4 + 2];
        o1.w = 2.f * acc[i][7] - xn - xxb[mbase + 64 + tx*4 + 3];
        *(float4*)&pd[((size_t)b * CHUNK + nl) * NPTS + mbase + tx*4] = o0;
        *(float4*)&pd[((size_t)b * CHUNK + nl) * NPTS + mbase + 64 + tx*4] = o1;
    }
}

// ---------------- per-row wave top-20 (largest pd; ties -> lower index) ----------------
__global__ __launch_bounds__(256) void topk_kernel(const float* __restrict__ pd,
                                                   int* __restrict__ idxout, int r0) {
    int wid = (blockIdx.x * 256 + threadIdx.x) >> 6;
    int lane = threadIdx.x & 63;
    int b = wid / CHUNK;
    int nl = wid % CHUNK;
    int n = r0 + nl;
    const float* row = pd + ((size_t)b * CHUNK + nl) * NPTS;

    float v[32];
    #pragma unroll
    for (int j = 0; j < 32; ++j) v[j] = row[lane + 64 * j];

    unsigned mask = 0u;
    int saved = 0;
    for (int t = 0; t < KNN; ++t) {
        float best = -INFINITY; int bj = 0;
        #pragma unroll
        for (int j = 0; j < 32; ++j) {
            bool ok = ((mask >> j) & 1u) == 0u;
            if (ok && v[j] > best) { best = v[j]; bj = j; }
        }
        int midx = lane + 64 * bj;
        #pragma unroll
        for (int off = 32; off > 0; off >>= 1) {
            float ov = __shfl_xor(best, off);
            int om = __shfl_xor(midx, off);
            if (ov > best || (ov == best && om < midx)) { best = ov; midx = om; }
        }
        if (lane == t) saved = midx;
        if ((midx & 63) == lane) mask |= 1u << (midx >> 6);
    }
    if (lane < KNN) idxout[((size_t)b * NPTS + n) * KNN + lane] = saved;
}

// ---------------- y = w_d * x ; z = (w_c - w_d) * x  (64n x 64o tile, 4x4/thread) ----------------
__global__ __launch_bounds__(256) void yz_gemm2(const float* __restrict__ x, int bstride, int C, int O,
                                                const float* __restrict__ w,
                                                float* __restrict__ y, float* __restrict__ z) {
    __shared__ float Xs[32][64];
    __shared__ float Wd[32][68];   // +4 pad: staging writes 32-way -> 4-way
    __shared__ float Wz[32][68];
    int b = blockIdx.z;
    int mbase = blockIdx.x * 64;
    int obase = blockIdx.y * 64;
    int tid = threadIdx.x;
    int nq = tid & 15, oq = tid >> 4;
    const float* xb = x + (size_t)b * bstride;
    int C2 = 2 * C;
    float accy[4][4] = {}, accz[4][4] = {};

    for (int c0 = 0; c0 < C; c0 += 32) {
        int KC = min(32, C - c0);
        for (int t = tid; t < 512; t += 256) {
            int cc = t >> 4, j4 = (t & 15) * 4;
            float4 v = make_float4(0.f, 0.f, 0.f, 0.f);
            if (cc < KC) v = *(const float4*)&xb[(size_t)(c0 + cc) * NPTS + mbase + j4];
            *(float4*)&Xs[cc][j4] = v;
        }
        for (int t = tid; t < 2048; t += 256) {
            int o = t >> 5, cc = t & 31;
            float wd = 0.f, wz = 0.f;
            if (cc < KC) {
                wd = w[(size_t)(obase + o) * C2 + c0 + cc];
                wz = w[(size_t)(obase + o) * C2 + C + c0 + cc] - wd;
            }
            Wd[cc][o] = wd; Wz[cc][o] = wz;
        }
        __syncthreads();
        for (int cc = 0; cc < KC; ++cc) {
            float xv[4], wdv[4], wzv[4];
            *(float4*)xv  = *(float4*)&Xs[cc][nq * 4];
            *(float4*)wdv = *(float4*)&Wd[cc][oq * 4];
            *(float4*)wzv = *(float4*)&Wz[cc][oq * 4];
            #pragma unroll
            for (int i = 0; i < 4; ++i)
                #pragma unroll
                for (int j = 0; j < 4; ++j) {
                    accy[i][j] += wdv[i] * xv[j];
                    accz[i][j] += wzv[i] * xv[j];
                }
        }
        __syncthreads();
    }

    #pragma unroll
    for (int i = 0; i < 4; ++i) {
        size_t off = ((size_t)b * O + obase + oq * 4 + i) * NPTS + mbase + nq * 4;
        *(float4*)&y[off] = make_float4(accy[i][0], accy[i][1], accy[i][2], accy[i][3]);
        *(float4*)&z[off] = make_float4(accz[i][0], accz[i][1], accz[i][2], accz[i][3]);
    }
}

// ---------------- gather + instnorm stats + leaky, 4 channels per block ----------------
__global__ __launch_bounds__(256) void gather_norm2(const float* __restrict__ y,
                                                    const float* __restrict__ z,
                                                    const int* __restrict__ idx,
                                                    float* __restrict__ cat, int coff, int O) {
    __shared__ float yt[NPTS][4];
    __shared__ float red[32];
    int og = blockIdx.x * 4, b = blockIdx.y;
    int tid = threadIdx.x;

    for (int n = tid; n < NPTS; n += 256) {
        float4 v;
        v.x = y[((size_t)b * O + og + 0) * NPTS + n];
        v.y = y[((size_t)b * O + og + 1) * NPTS + n];
        v.z = y[((size_t)b * O + og + 2) * NPTS + n];
        v.w = y[((size_t)b * O + og + 3) * NPTS + n];
        *(float4*)&yt[n][0] = v;
    }
    __syncthreads();

    float s1[4] = {0.f, 0.f, 0.f, 0.f}, s2[4] = {0.f, 0.f, 0.f, 0.f};
    float hm[4][8];
    for (int r = 0; r < 8; ++r) {
        int n = r * 256 + tid;
        const int* ip = idx + ((size_t)b * NPTS + n) * KNN;
        float zv[4], mx[4];
        #pragma unroll
        for (int j = 0; j < 4; ++j) {
            zv[j] = z[((size_t)b * O + og + j) * NPTS + n];
            mx[j] = -INFINITY;
        }
        #pragma unroll
        for (int k = 0; k < KNN; ++k) {
            int id = ip[k];
            float4 yv = *(float4*)&yt[id][0];
            float h0 = yv.x + zv[0]; s1[0] += h0; s2[0] += h0 * h0; mx[0] = fmaxf(mx[0], h0);
            float h1 = yv.y + zv[1]; s1[1] += h1; s2[1] += h1 * h1; mx[1] = fmaxf(mx[1], h1);
            float h2 = yv.z + zv[2]; s1[2] += h2; s2[2] += h2 * h2; mx[2] = fmaxf(mx[2], h2);
            float h3 = yv.w + zv[3]; s1[3] += h3; s2[3] += h3 * h3; mx[3] = fmaxf(mx[3], h3);
        }
        #pragma unroll
        for (int j = 0; j < 4; ++j) hm[j][r] = mx[j];
    }
    #pragma unroll
    for (int off = 32; off > 0; off >>= 1)
        #pragma unroll
        for (int j = 0; j < 4; ++j) {
            s1[j] += __shfl_xor(s1[j], off);
            s2[j] += __shfl_xor(s2[j], off);
        }
    int wv = tid >> 6, lane = tid & 63;
    if (lane == 0)
        #pragma unroll
        for (int j = 0; j < 4; ++j) { red[j * 8 + wv] = s1[j]; red[j * 8 + 4 + wv] = s2[j]; }
    __syncthreads();
    const float inv = 1.f / (float)(NPTS * KNN);
    #pragma unroll
    for (int j = 0; j < 4; ++j) {
        float S1 = red[j * 8 + 0] + red[j * 8 + 1] + red[j * 8 + 2] + red[j * 8 + 3];
        float S2 = red[j * 8 + 4] + red[j * 8 + 5] + red[j * 8 + 6] + red[j * 8 + 7];
        float mean = S1 * inv;
        float var = S2 * inv - mean * mean;
        float rs = 1.f / sqrtf(var + EPSI);
        float* dst = cat + ((size_t)b * 512 + coff + og + j) * NPTS;
        #pragma unroll
        for (int r = 0; r < 8; ++r) {
            float vv = (hm[j][r] - mean) * rs;
            dst[r * 256 + tid] = vv >= 0.f ? vv : SLOPE * vv;
        }
    }
}

// ---------------- w5 -> K-concat hi/lo bf16: wcat[o][0:512]=hi, [512:1024]=lo ----------------
__global__ __launch_bounds__(256) void w5_prep(const float* __restrict__ w5,
                                               unsigned short* __restrict__ wcat) {
    int i = blockIdx.x * 256 + threadIdx.x;
    int o = i >> 9, c = i & 511;
    float x = w5[i];
    unsigned short h = f2bf(x);
    wcat[(size_t)o * 1024 + c] = h;
    wcat[(size_t)o * 1024 + 512 + c] = f2bf(x - bf2f(h));
}

// ---------------- cat (B,512,N) -> point-major K-concat bf16 ----------------
__global__ __launch_bounds__(256) void catT_prep(const float* __restrict__ cat,
                                                 unsigned short* __restrict__ ct) {
    __shared__ float t[32][33];
    int b = blockIdx.z;
    int n0 = blockIdx.x * 32, c0 = blockIdx.y * 32;
    int tx = threadIdx.x & 31, ty = threadIdx.x >> 5;
    #pragma unroll
    for (int r = 0; r < 4; ++r) {
        int ci = ty + r * 8;
        t[ci][tx] = cat[((size_t)b * 512 + c0 + ci) * NPTS + n0 + tx];
    }
    __syncthreads();
    #pragma unroll
    for (int r = 0; r < 4; ++r) {
        int ni = ty + r * 8;
        float x = t[tx][ni];
        unsigned short h = f2bf(x);
        size_t off = ((size_t)b * NPTS + n0 + ni) * 1024 + c0 + tx;
        ct[off] = h;
        ct[off + 512] = f2bf(x - bf2f(h));
    }
}

// ---------------- final GEMM: h[b] = w5 (512x1024 bf16) x ct[b] (2048x1024 bf16)^T ----------------
__global__ __launch_bounds__(256, 2) void final_gemm_mfma2(const unsigned short* __restrict__ wcat,
                                                           const unsigned short* __restrict__ ct,
                                                           float* __restrict__ h) {
    __shared__ unsigned short smem[4 * 8192];   // [buf][A|B][128][64]
    int b = blockIdx.z;
    int nbase = blockIdx.x * 128, obase = blockIdx.y * 128;
    int tid = threadIdx.x;
    int w = tid >> 6, l = tid & 63;
    int wr = (w >> 1) * 64, wc = (w & 1) * 64;
    int lr = l & 15, lq = l >> 4;

    const unsigned short* Ag = wcat + (size_t)obase * 1024;
    const unsigned short* Bg = ct + ((size_t)b * NPTS + nbase) * 1024;

    int rw = l >> 3, g = l & 7, sg = g ^ rw;   // stage swizzle (involution)

    f32x4 acc[4][4] = {};

    auto STAGE = [&](int buf, int k0) {
        unsigned short* Ad = smem + buf * 16384;
        unsigned short* Bd = Ad + 8192;
        #pragma unroll
        for (int pass = 0; pass < 4; ++pass) {
            int rbase = pass * 32 + w * 8;
            int row = rbase + rw;
            gl_lds16(Ag + (size_t)row * 1024 + k0 + sg * 8, Ad + rbase * 64);
            gl_lds16(Bg + (size_t)row * 1024 + k0 + sg * 8, Bd + rbase * 64);
        }
    };

    STAGE(0, 0);
    __syncthreads();

    int cur = 0;
    for (int kt = 0; kt < 16; ++kt) {
        if (kt < 15) STAGE(cur ^ 1, (kt + 1) * 64);
        const unsigned short* As = smem + cur * 16384;
        const unsigned short* Bs = As + 8192;
        #pragma unroll
        for (int kk = 0; kk < 2; ++kk) {
            bf16x8 af[4], bf[4];
            int gl = kk * 4 + lq;
            #pragma unroll
            for (int mi = 0; mi < 4; ++mi) {
                int row = wr + mi * 16 + lr;
                af[mi] = *(const bf16x8*)&As[row * 64 + ((gl ^ (row & 7)) * 8)];
            }
            #pragma unroll
            for (int ni = 0; ni < 4; ++ni) {
                int row = wc + ni * 16 + lr;
                bf[ni] = *(const bf16x8*)&Bs[row * 64 + ((gl ^ (row & 7)) * 8)];
            }
            #pragma unroll
            for (int mi = 0; mi < 4; ++mi)
                #pragma unroll
                for (int ni = 0; ni < 4; ++ni)
                    acc[mi][ni] = __builtin_amdgcn_mfma_f32_16x16x32_bf16(af[mi], bf[ni], acc[mi][ni], 0, 0, 0);
        }
        __syncthreads();
        cur ^= 1;
    }

    int orow0 = obase + wr + lq * 4;
    int ncol0 = nbase + wc + lr;
    #pragma unroll
    for (int mi = 0; mi < 4; ++mi)
        #pragma unroll
        for (int r = 0; r < 4; ++r)
            #pragma unroll
            for (int ni = 0; ni < 4; ++ni)
                h[((size_t)b * 512 + orow0 + mi * 16 + r) * NPTS + ncol0 + ni * 16] = acc[mi][ni][r];
}

// ---------------- final instnorm over n + leaky ----------------
__global__ __launch_bounds__(256) void final_norm(const float* __restrict__ h,
                                                  float* __restrict__ out) {
    __shared__ float red[8];
    int o = blockIdx.x, b = blockIdx.y;
    int tid = threadIdx.x;
    const float* hr = h + ((size_t)b * 512 + o) * NPTS;
    float s1 = 0.f, s2 = 0.f;
    float v[8];
    #pragma unroll
    for (int r = 0; r < 8; ++r) {
        v[r] = hr[r * 256 + tid];
        s1 += v[r]; s2 += v[r] * v[r];
    }
    #pragma unroll
    for (int off = 32; off > 0; off >>= 1) {
        s1 += __shfl_xor(s1, off);
        s2 += __shfl_xor(s2, off);
    }
    int wv = tid >> 6, lane = tid & 63;
    if (lane == 0) { red[wv] = s1; red[4 + wv] = s2; }
    __syncthreads();
    float S1 = red[0] + red[1] + red[2] + red[3];
    float S2 = red[4] + red[5] + red[6] + red[7];
    const float inv = 1.f / (float)NPTS;
    float mean = S1 * inv;
    float var = S2 * inv - mean * mean;
    float rs = 1.f / sqrtf(var + EPSI);
    float* dst = out + ((size_t)b * 512 + o) * NPTS;
    #pragma unroll
    for (int r = 0; r < 8; ++r) {
        float vv = (v[r] - mean) * rs;
        dst[r * 256 + tid] = vv >= 0.f ? vv : SLOPE * vv;
    }
}

extern "C" void kernel_launch(void* const* d_in, const int* in_sizes, int n_in,
                              void* d_out, int out_size, void* d_ws, size_t ws_size,
                              hipStream_t stream) {
    const float* x_in = (const float*)d_in[0];
    const float* w1 = (const float*)d_in[1];
    const float* w2 = (const float*)d_in[2];
    const float* w3 = (const float*)d_in[3];
    const float* w4 = (const float*)d_in[4];
    const float* w5 = (const float*)d_in[5];
    float* out = (float*)d_out;
    float* ws = (float*)d_ws;

    // workspace (floats):
    // region [0, 8388608): pd chunk / y+z during layers; ct (bf16, 33.5MB) at final
    // idx 327680 ints; xx 16384; xc 49152; cat 8388608 (reused as h); wcat 1MB bf16
    float* region = ws;
    float* yb = region;
    float* zb = region + 4194304;
    float* pdb = region;
    int* idxb = (int*)(ws + 8388608);
    float* xxb = ws + 8388608 + 327680;
    float* xcb = xxb + NB * NPTS;
    float* cat = xcb + NB * 3 * NPTS;
    unsigned short* wcat = (unsigned short*)(cat + 8388608);
    unsigned short* ct = (unsigned short*)region;
    float* hb = cat;   // cat is dead after catT_prep

    transpose_kernel<<<NB * NPTS / 256, 256, 0, stream>>>(x_in, xcb);
    w5_prep<<<512 * 512 / 256, 256, 0, stream>>>(w5, wcat);

    const float* srcs[4] = {xcb, cat, cat + (size_t)64 * NPTS, cat + (size_t)128 * NPTS};
    int bstr[4] = {3 * NPTS, 512 * NPTS, 512 * NPTS, 512 * NPTS};
    int Cin[4] = {3, 64, 64, 128};
    int Oc[4] = {64, 64, 128, 256};
    const float* wl[4] = {w1, w2, w3, w4};
    int coffs[4] = {0, 64, 128, 256};

    for (int li = 0; li < 4; ++li) {
        xx_kernel<<<NB * NPTS / 256, 256, 0, stream>>>(srcs[li], bstr[li], Cin[li], xxb);
        for (int r0 = 0; r0 < NPTS; r0 += CHUNK) {
            pd_gemm3<<<dim3(NPTS / 128, CHUNK / 128, NB), 256, 0, stream>>>(
                srcs[li], bstr[li], Cin[li], xxb, pdb, r0);
            topk_kernel<<<NB * CHUNK / 4, 256, 0, stream>>>(pdb, idxb, r0);
        }
        yz_gemm2<<<dim3(NPTS / 64, Oc[li] / 64, NB), 256, 0, stream>>>(
            srcs[li], bstr[li], Cin[li], Oc[li], wl[li], yb, zb);
        gather_norm2<<<dim3(Oc[li] / 4, NB), 256, 0, stream>>>(yb, zb, idxb, cat, coffs[li], Oc[li]);
    }

    catT_prep<<<dim3(NPTS / 32, 512 / 32, NB), 256, 0, stream>>>(cat, ct);
    final_gemm_mfma2<<<dim3(NPTS / 128, 512 / 128, NB), 256, 0, stream>>>(wcat, ct, hb);
    final_norm<<<dim3(512, NB), 256, 0, stream>>>(hb, out);
}